// Round 3
// baseline (207.021 us; speedup 1.0000x reference)
//
#include <hip/hip_runtime.h>
#include <hip/hip_bf16.h>

#define T_ROWS 8192
#define K_DIM  1024
#define N_DIM  2048
#define G_NUM  8
#define CONVA_BLOCKS 2048   // (T*K/16)/256 -- 16 floats per thread
#define CONVB_BLOCKS 4096   // G*(K/64)*(N/64)

typedef __attribute__((ext_vector_type(8))) short short8;
typedef __attribute__((ext_vector_type(4))) float v4f;

// ---------- helpers ----------
__device__ __forceinline__ unsigned short f2bf(float x) {
  unsigned int u = __builtin_bit_cast(unsigned int, x);
  u += 0x7fffu + ((u >> 16) & 1u);   // round-to-nearest-even
  return (unsigned short)(u >> 16);
}
__device__ __forceinline__ unsigned int pk2(float a, float b) {
  return (unsigned int)f2bf(a) | ((unsigned int)f2bf(b) << 16);
}
__device__ __forceinline__ void async_cp16(const void* gsrc, void* ldst) {
  __builtin_amdgcn_global_load_lds(
      (const __attribute__((address_space(1))) void*)gsrc,
      (__attribute__((address_space(3))) void*)ldst, 16, 0, 0);
}

// ---------- fused convert, INTERLEAVED: bid%3==0 -> A-stream, else B-transpose ----
__global__ __launch_bounds__(256) void conv_fused(const float* __restrict__ A,
                                                  const float* __restrict__ B,
                                                  unsigned short* __restrict__ Ab,
                                                  unsigned short* __restrict__ Bt) {
  __shared__ float tile[64][65];   // B path only; +1 pad -> conflict-free
  const int bid = blockIdx.x;
  const int t = threadIdx.x;
  const int q3 = bid / 3, r3 = bid - q3 * 3;

  if (r3 == 0) {
    // ---- A fp32 -> bf16, same layout, 16 floats/thread ----
    size_t idx = (size_t)q3 * 256 + t;          // [0, 2048*256)
    const float4* src = (const float4*)A + idx * 4;
    float4 v0 = src[0], v1 = src[1], v2 = src[2], v3 = src[3];
    uint4 o0, o1;
    o0.x = pk2(v0.x, v0.y); o0.y = pk2(v0.z, v0.w);
    o0.z = pk2(v1.x, v1.y); o0.w = pk2(v1.z, v1.w);
    o1.x = pk2(v2.x, v2.y); o1.y = pk2(v2.z, v2.w);
    o1.z = pk2(v3.x, v3.y); o1.w = pk2(v3.z, v3.w);
    ((uint4*)Ab)[idx * 2]     = o0;
    ((uint4*)Ab)[idx * 2 + 1] = o1;
    return;
  }
  // ---- B[g][k][n] fp32 -> Bt[g][n][k] bf16 via padded-LDS 64x64 transpose ----
  const int bidx = 2 * q3 + (r3 - 1);           // [0, 4096)
  const int nt = bidx & 31;          // N/64
  const int kt = (bidx >> 5) & 15;   // K/64
  const int g  = bidx >> 9;          // G
  const int c4 = t & 15;
  const int r  = t >> 4;

  const float* src = B + ((size_t)g * K_DIM + (size_t)kt * 64) * N_DIM + (size_t)nt * 64;
#pragma unroll
  for (int i = 0; i < 4; ++i) {
    int k = r + i * 16;
    float4 v = *(const float4*)(src + (size_t)k * N_DIM + c4 * 4);
    tile[k][c4 * 4 + 0] = v.x; tile[k][c4 * 4 + 1] = v.y;
    tile[k][c4 * 4 + 2] = v.z; tile[k][c4 * 4 + 3] = v.w;
  }
  __syncthreads();
  unsigned short* dst = Bt + ((size_t)g * N_DIM + (size_t)nt * 64) * K_DIM + (size_t)kt * 64;
#pragma unroll
  for (int i = 0; i < 2; ++i) {
    int idx = t + i * 256;
    int n = idx >> 3;
    int seg = idx & 7;
    unsigned int u0 = pk2(tile[seg * 8 + 0][n], tile[seg * 8 + 1][n]);
    unsigned int u1 = pk2(tile[seg * 8 + 2][n], tile[seg * 8 + 3][n]);
    unsigned int u2 = pk2(tile[seg * 8 + 4][n], tile[seg * 8 + 5][n]);
    unsigned int u3 = pk2(tile[seg * 8 + 6][n], tile[seg * 8 + 7][n]);
    uint4 o; o.x = u0; o.y = u1; o.z = u2; o.w = u3;
    *(uint4*)(dst + (size_t)n * K_DIM + seg * 8) = o;
  }
}

// ---------- grouped bf16 MFMA GEMM, 256x256 tile, 8 waves, BK=32, 4-slot ring ----
// R3: move the (provably race-free) counted-vmcnt ring from the null quadrant
// (128^2 / 4 waves -- R1/R2 & m232: ~570 TF) to the proven one (256^2 / 8 waves
// -- m248 grouped K=1024 full stack: 848 TF). Per phase per wave:
// 12 ds_read_b128 + 4 global_load_lds + 32 MFMA (ratio 2.67 vs 2.0 at 128^2),
// setprio(1) around the MFMA cluster, vmcnt(8) counted waits (never 0 mid-loop).
// Hazard proof: slot-reuse distance 4; each wave issues exactly 4 loads/tile in
// identical order, so its own vmcnt(8) (= tiles t+1,t+2 outstanding) implies its
// tile-t loads landed; barrier then implies ALL waves' tile-t loads landed.
// Writes at step t target slot (t+3)&3 = (t-1)&3, whose reads completed before
// this barrier. LDS swizzle (both-sides 2-bit XOR, rule 21): phys_chunk =
// logical ^ s(row), s(r) = (r ^ (r>>2)) & 3; dest stays linear for gload_lds,
// source pre-swizzled, reads XOR the same involution. Uniform 8 dw/bank at
// full-wave AND quarter-wave granularity.
__global__ __launch_bounds__(512) void gemm_kernel(const unsigned short* __restrict__ Ab,
                                                   const unsigned short* __restrict__ Btb,
                                                   const int* __restrict__ offs,
                                                   float* __restrict__ out) {
  __shared__ char lds[131072];   // 4 slots * 32KB: per slot A 256x32 bf16 (16KB) + B (16KB)
  const int t = threadIdx.x;

  const int b = blockIdx.x;            // 320 blocks = 8 xcd * 5 mslot * 8 ntile
  const int xcd = b & 7;
  const int j = b >> 3;                // [0,40)
  const int mslot = xcd * 5 + (j >> 3);
  const int n0 = (j & 7) * 256;

  // slot -> (group, row tile of 256); wave-uniform. Max Sum(ceil) = 39 < 40.
  int prev = 0, cum = 0, row0 = 0, row_end = 0, g = 0, found = 0;
#pragma unroll
  for (int gg = 0; gg < G_NUM; ++gg) {
    int e = offs[gg];
    int tiles = (e - prev + 255) >> 8;
    if (!found && mslot < cum + tiles) {
      found = 1; g = gg; row0 = prev + (mslot - cum) * 256; row_end = e;
    }
    cum += tiles;
    prev = e;
  }
  if (!found) return;   // whole block exits uniformly (no barrier executed)

  const int lane = t & 63;
  const int wv = t >> 6;     // 0..7
  const int wm = wv & 1;     // M half: rows wm*128..+128
  const int wn = wv >> 1;    // N quarter: cols wn*64..+64

  // ---- staging: thread t stages LDS bytes t*16 of each 8KB region.
  // region layout per slot: A rows [0,128) @0, A rows [128,256) @8192,
  //                         B rows [0,128) @16384, B rows [128,256) @24576.
  // dest (row = rq = t>>2, phys chunk = t&3) -> source logical chunk (t&3)^s(rq).
  const int rq = t >> 2;     // 0..127
  const int t4 = (t & 3) ^ ((rq ^ (rq >> 2)) & 3);
  int rA0 = row0 + rq;       if (rA0 > T_ROWS - 1) rA0 = T_ROWS - 1;  // tail clamp
  int rA1 = row0 + 128 + rq; if (rA1 > T_ROWS - 1) rA1 = T_ROWS - 1;
  const unsigned short* aSrc0 = Ab + (size_t)rA0 * K_DIM + t4 * 8;
  const unsigned short* aSrc1 = Ab + (size_t)rA1 * K_DIM + t4 * 8;
  const unsigned short* bSrc0 = Btb + ((size_t)g * N_DIM + n0 + rq) * K_DIM + t4 * 8;
  const unsigned short* bSrc1 = Btb + ((size_t)g * N_DIM + n0 + 128 + rq) * K_DIM + t4 * 8;

  // fragment-read bases: logical chunk = lane>>4, phys = logical ^ s(lane&15);
  // s(row) is invariant under +16/+64/+128 row offsets (they are 0 mod 4 after >>2).
  const int lr = lane & 15;
  const int phx = ((lane >> 4) ^ ((lr ^ (lr >> 2)) & 3)) << 4;
  const int arow = (wm * 128 + lr) * 64 + phx;           // + mf*1024, mf 0..7
  const int brow = (wn * 64 + lr) * 64 + phx + 16384;    // + nf*1024, nf 0..3

  v4f acc[8][4];
#pragma unroll
  for (int i = 0; i < 8; ++i)
#pragma unroll
    for (int j2 = 0; j2 < 4; ++j2)
#pragma unroll
      for (int r = 0; r < 4; ++r) acc[i][j2][r] = 0.0f;

#define ISSUE_T(TILE, S2)                                                  \
  do {                                                                     \
    char* base_ = (char*)lds + (S2) * 32768 + t * 16;                      \
    async_cp16(aSrc0 + (TILE) * 32, base_);                                \
    async_cp16(aSrc1 + (TILE) * 32, base_ + 8192);                         \
    async_cp16(bSrc0 + (TILE) * 32, base_ + 16384);                        \
    async_cp16(bSrc1 + (TILE) * 32, base_ + 24576);                        \
  } while (0)

#define PHASE_T(S, TILE, VM)                                               \
  do {                                                                     \
    asm volatile("s_waitcnt vmcnt(" #VM ")" ::: "memory");                 \
    __builtin_amdgcn_s_barrier();                                          \
    __builtin_amdgcn_sched_barrier(0);                                     \
    if ((TILE) >= 0) ISSUE_T(TILE, ((S) + 3) & 3);                         \
    short8 af_[8], bf_[4];                                                 \
    {                                                                      \
      const char* ab_ = (const char*)lds + (S) * 32768 + arow;             \
      const char* bb_ = (const char*)lds + (S) * 32768 + brow;             \
      _Pragma("unroll")                                                    \
      for (int mf = 0; mf < 8; ++mf) af_[mf] = *(const short8*)(ab_ + mf * 1024); \
      _Pragma("unroll")                                                    \
      for (int nf = 0; nf < 4; ++nf) bf_[nf] = *(const short8*)(bb_ + nf * 1024); \
    }                                                                      \
    __builtin_amdgcn_s_setprio(1);                                         \
    _Pragma("unroll")                                                      \
    for (int mf = 0; mf < 8; ++mf)                                         \
      _Pragma("unroll")                                                    \
      for (int nf = 0; nf < 4; ++nf)                                       \
        acc[mf][nf] = __builtin_amdgcn_mfma_f32_16x16x32_bf16(af_[mf], bf_[nf], acc[mf][nf], 0, 0, 0); \
    __builtin_amdgcn_s_setprio(0);                                         \
    __builtin_amdgcn_sched_barrier(0);                                     \
  } while (0)

  // prologue: fill ring slots 0..2 (12 loads/wave in flight)
  ISSUE_T(0, 0);
  ISSUE_T(1, 1);
  ISSUE_T(2, 2);

  // main loop: steps 0..27 compute tile t (slot t&3), issue tile t+3 (tiles 3..30).
  // vmcnt(8): 4 loads/tile/wave -> only tiles t+1,t+2 may stay outstanding.
#pragma unroll 1
  for (int tb = 0; tb < 28; tb += 4) {
    PHASE_T(0, tb + 3, 8);
    PHASE_T(1, tb + 4, 8);
    PHASE_T(2, tb + 5, 8);
    PHASE_T(3, tb + 6, 8);
  }
  // peeled tail: steps 28..31; step 28 issues tile 31; derived waits 8 -> 8 -> 4 -> 0
  PHASE_T(0, 31, 8);
  PHASE_T(1, -1, 8);
  PHASE_T(2, -1, 4);
  PHASE_T(3, -1, 0);

#undef PHASE_T
#undef ISSUE_T

  // epilogue: C/D layout col=lane&15, row=(lane>>4)*4+reg
  const int colBase = n0 + wn * 64 + lr;
  const int rowBase = row0 + wm * 128 + ((lane >> 4) << 2);
#pragma unroll
  for (int mf = 0; mf < 8; ++mf) {
#pragma unroll
    for (int nf = 0; nf < 4; ++nf) {
      int c = colBase + nf * 16;
#pragma unroll
      for (int r = 0; r < 4; ++r) {
        int rr = rowBase + mf * 16 + r;
        if (rr < row_end) out[(size_t)rr * N_DIM + c] = acc[mf][nf][r];
      }
    }
  }
}

// ---------- fallback (workspace too small): fp32 vector GEMM ----------
__global__ __launch_bounds__(256) void fallback_kernel(const float* __restrict__ A,
                                                       const float* __restrict__ B,
                                                       const int* __restrict__ offs,
                                                       float* __restrict__ out) {
  int r = blockIdx.y;
  int c = blockIdx.x * 256 + threadIdx.x;
  int g = 0;
#pragma unroll
  for (int i = 0; i < G_NUM; ++i) g += (offs[i] <= r);
  const float* a = A + (size_t)r * K_DIM;
  const float* b = B + (size_t)g * K_DIM * N_DIM + c;
  float s = 0.f;
  for (int k = 0; k < K_DIM; ++k) s += a[k] * b[(size_t)k * N_DIM];
  out[(size_t)r * N_DIM + c] = s;
}

extern "C" void kernel_launch(void* const* d_in, const int* in_sizes, int n_in,
                              void* d_out, int out_size, void* d_ws, size_t ws_size,
                              hipStream_t stream) {
  const float* A = (const float*)d_in[0];
  const float* B = (const float*)d_in[1];
  const int* offs = (const int*)d_in[2];
  float* out = (float*)d_out;

  size_t need = ((size_t)T_ROWS * K_DIM + (size_t)G_NUM * K_DIM * N_DIM) * 2;
  if (ws_size < need) {
    dim3 grid(N_DIM / 256, T_ROWS);
    fallback_kernel<<<grid, 256, 0, stream>>>(A, B, offs, out);
    return;
  }
  unsigned short* Ab = (unsigned short*)d_ws;
  unsigned short* Btb = Ab + (size_t)T_ROWS * K_DIM;

  conv_fused<<<CONVA_BLOCKS + CONVB_BLOCKS, 256, 0, stream>>>(A, B, Ab, Btb);
  // 8 xcd * 5 mslot * 8 ntile = 320 blocks; XCD-contiguous mslot mapping
  gemm_kernel<<<8 * 5 * 8, 512, 0, stream>>>(Ab, Btb, offs, out);
}

// Round 4
// 191.555 us; speedup vs baseline: 1.0807x; 1.0807x over previous
//
#include <hip/hip_runtime.h>
#include <hip/hip_bf16.h>

#define T_ROWS 8192
#define K_DIM  1024
#define N_DIM  2048
#define G_NUM  8
#define CONVA_BLOCKS 2048   // (T*K/16)/256 -- 16 floats per thread
#define CONVB_BLOCKS 4096   // G*(K/64)*(N/64)

typedef __attribute__((ext_vector_type(8))) short short8;
typedef __attribute__((ext_vector_type(4))) float v4f;

// ---------- helpers ----------
__device__ __forceinline__ unsigned short f2bf(float x) {
  unsigned int u = __builtin_bit_cast(unsigned int, x);
  u += 0x7fffu + ((u >> 16) & 1u);   // round-to-nearest-even
  return (unsigned short)(u >> 16);
}
__device__ __forceinline__ unsigned int pk2(float a, float b) {
  return (unsigned int)f2bf(a) | ((unsigned int)f2bf(b) << 16);
}
__device__ __forceinline__ void async_cp16(const void* gsrc, void* ldst) {
  __builtin_amdgcn_global_load_lds(
      (const __attribute__((address_space(1))) void*)gsrc,
      (__attribute__((address_space(3))) void*)ldst, 16, 0, 0);
}

// ---------- fused convert, INTERLEAVED: bid%3==0 -> A-stream, else B-transpose ----
__global__ __launch_bounds__(256) void conv_fused(const float* __restrict__ A,
                                                  const float* __restrict__ B,
                                                  unsigned short* __restrict__ Ab,
                                                  unsigned short* __restrict__ Bt) {
  __shared__ float tile[64][65];   // B path only; +1 pad -> conflict-free
  const int bid = blockIdx.x;
  const int t = threadIdx.x;
  const int q3 = bid / 3, r3 = bid - q3 * 3;

  if (r3 == 0) {
    // ---- A fp32 -> bf16, same layout, 16 floats/thread ----
    size_t idx = (size_t)q3 * 256 + t;          // [0, 2048*256)
    const float4* src = (const float4*)A + idx * 4;
    float4 v0 = src[0], v1 = src[1], v2 = src[2], v3 = src[3];
    uint4 o0, o1;
    o0.x = pk2(v0.x, v0.y); o0.y = pk2(v0.z, v0.w);
    o0.z = pk2(v1.x, v1.y); o0.w = pk2(v1.z, v1.w);
    o1.x = pk2(v2.x, v2.y); o1.y = pk2(v2.z, v2.w);
    o1.z = pk2(v3.x, v3.y); o1.w = pk2(v3.z, v3.w);
    ((uint4*)Ab)[idx * 2]     = o0;
    ((uint4*)Ab)[idx * 2 + 1] = o1;
    return;
  }
  // ---- B[g][k][n] fp32 -> Bt[g][n][k] bf16 via padded-LDS 64x64 transpose ----
  const int bidx = 2 * q3 + (r3 - 1);           // [0, 4096)
  const int nt = bidx & 31;          // N/64
  const int kt = (bidx >> 5) & 15;   // K/64
  const int g  = bidx >> 9;          // G
  const int c4 = t & 15;
  const int r  = t >> 4;

  const float* src = B + ((size_t)g * K_DIM + (size_t)kt * 64) * N_DIM + (size_t)nt * 64;
#pragma unroll
  for (int i = 0; i < 4; ++i) {
    int k = r + i * 16;
    float4 v = *(const float4*)(src + (size_t)k * N_DIM + c4 * 4);
    tile[k][c4 * 4 + 0] = v.x; tile[k][c4 * 4 + 1] = v.y;
    tile[k][c4 * 4 + 2] = v.z; tile[k][c4 * 4 + 3] = v.w;
  }
  __syncthreads();
  unsigned short* dst = Bt + ((size_t)g * N_DIM + (size_t)nt * 64) * K_DIM + (size_t)kt * 64;
#pragma unroll
  for (int i = 0; i < 2; ++i) {
    int idx = t + i * 256;
    int n = idx >> 3;
    int seg = idx & 7;
    unsigned int u0 = pk2(tile[seg * 8 + 0][n], tile[seg * 8 + 1][n]);
    unsigned int u1 = pk2(tile[seg * 8 + 2][n], tile[seg * 8 + 3][n]);
    unsigned int u2 = pk2(tile[seg * 8 + 4][n], tile[seg * 8 + 5][n]);
    unsigned int u3 = pk2(tile[seg * 8 + 6][n], tile[seg * 8 + 7][n]);
    uint4 o; o.x = u0; o.y = u1; o.z = u2; o.w = u3;
    *(uint4*)(dst + (size_t)n * K_DIM + seg * 8) = o;
  }
}

// ---------- grouped bf16 MFMA GEMM, 128x128 tile, BK=64 (R0 structure) ----------
// R4: R0 structure restored verbatim (52 us known-good; the R1-R3 pipelined
// ring family measured 60-72 us -- dead at this problem's block counts).
// Single change vs R0: __launch_bounds__(256, 4).
//   gfx950 has a UNIFIED VGPR/AGPR file; R0 allocated 72 arch VGPR + 64 AGPR
//   (acc) = 136 regs/wave -> occupancy bucket 2-3 waves/SIMD (~3 blocks/CU,
//   matches the measured 18% OccupancyPercent). Requesting 4 waves/EU caps the
//   unified budget at 512/4 = 128 regs: 64 AGPR + <=64 arch VGPR (compiler
//   must shave 8 arch regs). Crossing the 128-reg cliff -> 4 blocks/CU (+33%
//   TLP, or 2x if the bucket boundary is exactly 128), covering the per-K-step
//   global_load_lds drain stall with more resident waves.
__global__ __launch_bounds__(256, 4) void gemm_kernel(const unsigned short* __restrict__ Ab,
                                                      const unsigned short* __restrict__ Btb,
                                                      const int* __restrict__ offs,
                                                      float* __restrict__ out) {
  __shared__ unsigned short As[128 * 64];
  __shared__ unsigned short Bs[128 * 64];
  const int t = threadIdx.x;

  const int b = blockIdx.x;
  const int xcd = b & 7;
  const int j = b >> 3;              // [0,144)
  const int mslot = xcd * 9 + (j >> 4);
  const int n0 = (j & 15) * 128;

  // slot -> (group, row tile); wave-uniform
  int prev = 0, cum = 0, row0 = 0, row_end = 0, g = 0, found = 0;
#pragma unroll
  for (int gg = 0; gg < G_NUM; ++gg) {
    int e = offs[gg];
    int tiles = (e - prev + 127) >> 7;
    if (!found && mslot < cum + tiles) {
      found = 1; g = gg; row0 = prev + (mslot - cum) * 128; row_end = e;
    }
    cum += tiles;
    prev = e;
  }
  if (!found) return;

  const int lane = t & 63;
  const int wv = t >> 6;
  const int wm = wv & 1;
  const int wn = wv >> 1;
  const int srcChunk = (t & 7) ^ ((t >> 3) & 7);  // XOR swizzle, matches frag-read side

  // hoisted global source pointers (k0-invariant) and LDS destinations
  const unsigned short* aSrc[4];
  const unsigned short* bSrc[4];
  char* aDst[4];
  char* bDst[4];
#pragma unroll
  for (int c = 0; c < 4; ++c) {
    int rl = c * 32 + (t >> 3);
    int rA = row0 + rl; if (rA > T_ROWS - 1) rA = T_ROWS - 1;  // tail clamp (store-masked)
    aSrc[c] = Ab + (size_t)rA * K_DIM + srcChunk * 8;
    bSrc[c] = Btb + ((size_t)g * N_DIM + n0 + rl) * K_DIM + srcChunk * 8;
    aDst[c] = (char*)As + c * 4096 + t * 16;
    bDst[c] = (char*)Bs + c * 4096 + t * 16;
  }

  v4f acc[4][4];
#pragma unroll
  for (int i = 0; i < 4; ++i)
#pragma unroll
    for (int j2 = 0; j2 < 4; ++j2)
#pragma unroll
      for (int r = 0; r < 4; ++r) acc[i][j2][r] = 0.0f;

  // peel: prefetch k0 = 0
#pragma unroll
  for (int c = 0; c < 4; ++c) {
    async_cp16(aSrc[c], aDst[c]);
    async_cp16(bSrc[c], bDst[c]);
  }

  for (int k0 = 0; k0 < K_DIM; k0 += 64) {
    __syncthreads();   // vmcnt(0) drain -> LDS tile ready
#pragma unroll
    for (int ks = 0; ks < 2; ++ks) {
      short8 a[4], bfr[4];
      int chBase = (lane >> 4) + ks * 4;
      int chPhys = chBase ^ (lane & 7);
#pragma unroll
      for (int im = 0; im < 4; ++im) {
        int row = wm * 64 + im * 16 + (lane & 15);
        a[im] = *(const short8*)((const char*)As + row * 128 + chPhys * 16);
      }
#pragma unroll
      for (int in = 0; in < 4; ++in) {
        int row = wn * 64 + in * 16 + (lane & 15);
        bfr[in] = *(const short8*)((const char*)Bs + row * 128 + chPhys * 16);
      }
#pragma unroll
      for (int im = 0; im < 4; ++im)
#pragma unroll
        for (int in = 0; in < 4; ++in)
          acc[im][in] = __builtin_amdgcn_mfma_f32_16x16x32_bf16(a[im], bfr[in], acc[im][in], 0, 0, 0);
    }
    if (k0 + 64 < K_DIM) {
      __syncthreads();   // all waves done reading LDS
      int koff = k0 + 64;
#pragma unroll
      for (int c = 0; c < 4; ++c) {
        async_cp16(aSrc[c] + koff, aDst[c]);
        async_cp16(bSrc[c] + koff, bDst[c]);
      }
    }
  }

  // epilogue: C/D layout col=lane&15, row=(lane>>4)*4+reg
  const int colBase = n0 + wn * 64 + (lane & 15);
  const int rowBase = row0 + wm * 64 + ((lane >> 4) << 2);
#pragma unroll
  for (int im = 0; im < 4; ++im) {
#pragma unroll
    for (int in = 0; in < 4; ++in) {
      int c = colBase + in * 16;
#pragma unroll
      for (int r = 0; r < 4; ++r) {
        int rr = rowBase + im * 16 + r;
        if (rr < row_end) out[(size_t)rr * N_DIM + c] = acc[im][in][r];
      }
    }
  }
}

// ---------- fallback (workspace too small): fp32 vector GEMM ----------
__global__ __launch_bounds__(256) void fallback_kernel(const float* __restrict__ A,
                                                       const float* __restrict__ B,
                                                       const int* __restrict__ offs,
                                                       float* __restrict__ out) {
  int r = blockIdx.y;
  int c = blockIdx.x * 256 + threadIdx.x;
  int g = 0;
#pragma unroll
  for (int i = 0; i < G_NUM; ++i) g += (offs[i] <= r);
  const float* a = A + (size_t)r * K_DIM;
  const float* b = B + (size_t)g * K_DIM * N_DIM + c;
  float s = 0.f;
  for (int k = 0; k < K_DIM; ++k) s += a[k] * b[(size_t)k * N_DIM];
  out[(size_t)r * N_DIM + c] = s;
}

extern "C" void kernel_launch(void* const* d_in, const int* in_sizes, int n_in,
                              void* d_out, int out_size, void* d_ws, size_t ws_size,
                              hipStream_t stream) {
  const float* A = (const float*)d_in[0];
  const float* B = (const float*)d_in[1];
  const int* offs = (const int*)d_in[2];
  float* out = (float*)d_out;

  size_t need = ((size_t)T_ROWS * K_DIM + (size_t)G_NUM * K_DIM * N_DIM) * 2;
  if (ws_size < need) {
    dim3 grid(N_DIM / 256, T_ROWS);
    fallback_kernel<<<grid, 256, 0, stream>>>(A, B, offs, out);
    return;
  }
  unsigned short* Ab = (unsigned short*)d_ws;
  unsigned short* Btb = Ab + (size_t)T_ROWS * K_DIM;

  conv_fused<<<CONVA_BLOCKS + CONVB_BLOCKS, 256, 0, stream>>>(A, B, Ab, Btb);
  // linear grid, XCD-swizzled inside: 8 * 9 * 16 = 1152 blocks
  gemm_kernel<<<8 * 9 * 16, 256, 0, stream>>>(Ab, Btb, offs, out);
}